// Round 7
// baseline (118.074 us; speedup 1.0000x reference)
//
#include <hip/hip_runtime.h>
#include <math.h>
#include <stdint.h>

typedef uint32_t u32;
typedef _Float16 half2v __attribute__((ext_vector_type(2)));
typedef uint32_t u32x4 __attribute__((ext_vector_type(4)));

#define KK 5
#define PADK 2
#define C_IN 8
#define O_OUT 8
#define HH 512
#define WW 512
#define TH 8
#define TW 128
#define LROWS (TH + 2 * PADK)   // 12
#define LPAIRS 68               // dwords per row
#define NW (O_OUT * C_IN * KK * KK)  // 1600
#define WROW (O_OUT * KK)            // 40 dwords per (c,dy)

static __device__ __forceinline__ half2v bc_h2(u32 u) {
    return __builtin_bit_cast(half2v, u);
}
// Forced packed f16 ops (VOP3P) — immune to scalarization.
static __device__ __forceinline__ u32 pk_add(u32 a, u32 b) {
    u32 d; asm("v_pk_add_f16 %0, %1, %2" : "=v"(d) : "v"(a), "v"(b)); return d;
}
static __device__ __forceinline__ u32 pk_max(u32 a, u32 b) {
    u32 d; asm("v_pk_max_f16 %0, %1, %2" : "=v"(d) : "v"(a), "v"(b)); return d;
}

// ---- prep: fp32 weights -> packed (h,h) f16, reordered to [c][dy][o][dx] ----
__global__ void prep_weights_kernel(const float* __restrict__ w,
                                    u32* __restrict__ wp) {
    int i = blockIdx.x * 256 + threadIdx.x;   // i over (o,c,dy,dx)
    if (i < NW) {
        int dx = i % KK;
        int t  = i / KK;
        int dy = t % KK;  t /= KK;
        int c  = t % C_IN;
        int o  = t / C_IN;
        _Float16 h = (_Float16)w[i];
        uint16_t hb = __builtin_bit_cast(uint16_t, h);
        int j = ((c * KK + dy) * O_OUT + o) * KK + dx;
        wp[j] = ((u32)hb << 16) | (u32)hb;
    }
}

// Load one (c,dy) weight row (40 dwords = 160 B) into VGPRs via VMEM.
// Address laundered so the compiler cannot prove uniformity -> emits
// global_load_dwordx4 (vmcnt domain, counted waits) instead of s_load
// (lgkmcnt domain, out-of-order -> full drains).
template <bool USE_WS>
static __device__ __forceinline__ void loadw(u32x4 (&dst)[10], const u32* wq,
                                             int c, int dy,
                                             const float* wf) {
    if constexpr (USE_WS) {
        uintptr_t q = (uintptr_t)(wq + (c * KK + dy) * WROW);
        asm("" : "+v"(q));   // launder uniformity
        const u32x4* p = (const u32x4*)q;
        #pragma unroll
        for (int k = 0; k < 10; ++k) dst[k] = p[k];
    } else {
        #pragma unroll
        for (int o = 0; o < O_OUT; ++o) {
            #pragma unroll
            for (int dx = 0; dx < KK; ++dx) {
                float f = wf[((o * C_IN + c) * KK + dy) * KK + dx];
                _Float16 h = (_Float16)f;
                uint16_t hb = __builtin_bit_cast(uint16_t, h);
                int k = o * KK + dx;
                dst[k >> 2][k & 3] = ((u32)hb << 16) | (u32)hb;
            }
        }
    }
}

template <bool USE_WS>
__global__ __launch_bounds__(512, 4)
void dil_kernel(const float* __restrict__ x,
                const float* __restrict__ wf,
                const u32* __restrict__ wq,
                float* __restrict__ out) {
    __shared__ u32 lds[C_IN][LROWS][LPAIRS];   // 26,112 B

    const int tid = threadIdx.x;
    const int w0 = blockIdx.x * TW;
    const int h0 = blockIdx.y * TH;
    const int n  = blockIdx.z;

    // ---- stage x tile into LDS as packed f16 pairs, zero halo ----
    const float* xn = x + (size_t)n * (C_IN * HH * WW);
    for (int idx = tid; idx < C_IN * LROWS * LPAIRS; idx += 512) {
        int c   = idx / (LROWS * LPAIRS);
        int rem = idx - c * (LROWS * LPAIRS);
        int r   = rem / LPAIRS;
        int jp  = rem - r * LPAIRS;
        int gh = h0 - PADK + r;
        int gw = w0 - PADK + 2 * jp;
        float v0 = 0.f, v1 = 0.f;
        if ((unsigned)gh < (unsigned)HH) {
            const float* row = xn + ((size_t)c * HH + gh) * WW;
            if ((unsigned)gw < (unsigned)WW) v0 = row[gw];
            if ((unsigned)(gw + 1) < (unsigned)WW) v1 = row[gw + 1];
        }
        _Float16 a = (_Float16)v0, b = (_Float16)v1;
        u32 u = ((u32)__builtin_bit_cast(uint16_t, b) << 16) |
                (u32)__builtin_bit_cast(uint16_t, a);
        (&lds[0][0][0])[idx] = u;
    }
    __syncthreads();

    // wave = one output row; lane = one f16 pair (2 pixels), all 8 o
    const int tx  = tid & 63;
    const int wid = tid >> 6;

    u32 acc[O_OUT];
    #pragma unroll
    for (int o = 0; o < O_OUT; ++o) acc[o] = 0xFC00FC00u;  // (-inf,-inf)

#define DYB(dy_, B) { \
    u32 u0 = u_[dy_][0], u1 = u_[dy_][1], u2 = u_[dy_][2]; \
    u32 s0 = (u0 >> 16) | (u1 << 16); \
    u32 s1 = (u1 >> 16) | (u2 << 16); \
    _Pragma("unroll") \
    for (int o = 0; o < O_OUT; ++o) { \
        u32 t0 = pk_add(B[(o*5+0)>>2][(o*5+0)&3], u0); \
        u32 t1 = pk_add(B[(o*5+1)>>2][(o*5+1)&3], s0); \
        u32 t2 = pk_add(B[(o*5+2)>>2][(o*5+2)&3], u1); \
        u32 t3 = pk_add(B[(o*5+3)>>2][(o*5+3)&3], s1); \
        u32 t4 = pk_add(B[(o*5+4)>>2][(o*5+4)&3], u2); \
        acc[o] = pk_max(acc[o], \
                 pk_max(pk_max(pk_max(t0, t1), pk_max(t2, t3)), t4)); \
    } \
}

// Buffer invariant: entering CSTEP, B0 holds (c_, dy=0).
// Each step prefetches the next row into the buffer just consumed.
#define CSTEP(c_, cn_, B0, B1) { \
    u32 u_[KK][3]; \
    _Pragma("unroll") \
    for (int dy = 0; dy < KK; ++dy) { \
        const u32* lrow = &lds[c_][wid + dy][tx]; \
        u_[dy][0] = lrow[0]; u_[dy][1] = lrow[1]; u_[dy][2] = lrow[2]; \
    } \
    loadw<USE_WS>(B1, wq, c_, 1, wf);  DYB(0, B0) \
    loadw<USE_WS>(B0, wq, c_, 2, wf);  DYB(1, B1) \
    loadw<USE_WS>(B1, wq, c_, 3, wf);  DYB(2, B0) \
    loadw<USE_WS>(B0, wq, c_, 4, wf);  DYB(3, B1) \
    loadw<USE_WS>(B1, wq, cn_, 0, wf); DYB(4, B0) \
}

    u32x4 wrA[10], wrB[10];
    const int c0 = wid & 7;
    loadw<USE_WS>(wrA, wq, c0, 0, wf);   // prologue: (c0, dy0) -> wrA

    for (int cb = 0; cb < C_IN; cb += 2) {
        const int cA = (cb + 0 + wid) & 7;   // per-wave channel rotation
        const int cB = (cb + 1 + wid) & 7;
        const int cC = (cb + 2 + wid) & 7;   // wraps on last iter (unused data)
        CSTEP(cA, cB, wrA, wrB)
        CSTEP(cB, cC, wrB, wrA)
    }
#undef CSTEP
#undef DYB

    // ---- store: 2 consecutive pixels -> one float2, coalesced ----
    float* onp = out + (size_t)n * (O_OUT * HH * WW);
    const int h = h0 + wid;
    const int wcol = w0 + 2 * tx;
    #pragma unroll
    for (int o = 0; o < O_OUT; ++o) {
        half2v a = bc_h2(acc[o]);
        float2 r;
        r.x = (float)a.x;
        r.y = (float)a.y;
        *(float2*)(&onp[((size_t)o * HH + h) * WW + wcol]) = r;
    }
}

extern "C" void kernel_launch(void* const* d_in, const int* in_sizes, int n_in,
                              void* d_out, int out_size, void* d_ws, size_t ws_size,
                              hipStream_t stream) {
    const float* x   = (const float*)d_in[0];
    const float* wgt = (const float*)d_in[1];
    float* out = (float*)d_out;

    dim3 grid(WW / TW, HH / TH, 4);   // (4, 64, 4) = 1024 blocks x 512 thr
    dim3 block(512);

    if (ws_size >= (size_t)NW * 4) {
        u32* wp = (u32*)d_ws;
        prep_weights_kernel<<<(NW + 255) / 256, 256, 0, stream>>>(wgt, wp);
        dil_kernel<true><<<grid, block, 0, stream>>>(x, wgt, wp, out);
    } else {
        dil_kernel<false><<<grid, block, 0, stream>>>(x, wgt, nullptr, out);
    }
}

// Round 8
// 72.294 us; speedup vs baseline: 1.6332x; 1.6332x over previous
//
#include <hip/hip_runtime.h>
#include <stdint.h>

typedef uint32_t u32;
typedef _Float16 half2v __attribute__((ext_vector_type(2)));
typedef uint32_t u32x4 __attribute__((ext_vector_type(4)));
typedef uint32_t u32x2 __attribute__((ext_vector_type(2)));

#define KK 5
#define PADK 2
#define C_IN 8
#define O_OUT 8
#define HH 512
#define WW 512
#define TH 8
#define TW 128
#define LROWS 12                 // TH + 4
#define LPAIRS 68                // (TW+4)/2 = 66, padded to 68 dwords
#define WCHUNK 12                // 10 weight dwords + 2 pad -> 48B stride (16-aligned)
#define NW (O_OUT * C_IN * KK * KK)   // 1600
#define XWORDS (C_IN * LROWS * LPAIRS)

// Forced packed f16 ops (VOP3P).
static __device__ __forceinline__ u32 pk_add(u32 a, u32 b) {
    u32 d; asm("v_pk_add_f16 %0, %1, %2" : "=v"(d) : "v"(a), "v"(b)); return d;
}
static __device__ __forceinline__ u32 pk_max(u32 a, u32 b) {
    u32 d; asm("v_pk_max_f16 %0, %1, %2" : "=v"(d) : "v"(a), "v"(b)); return d;
}

__global__ __launch_bounds__(512, 4)
void dil_kernel(const float* __restrict__ x,
                const float* __restrict__ wf,
                float* __restrict__ out) {
    // ALL main-loop operands come from LDS: DS pipe is in-order, so the
    // compiler can use counted lgkmcnt(N) waits. No SMEM (out-of-order,
    // forces lgkmcnt(0) full drains) and no VMEM in the loop.
    __shared__ u32 xlds[C_IN][LROWS][LPAIRS];       // 26,112 B
    __shared__ u32 wlds[C_IN * 4 * KK * WCHUNK];    // 1920 dw = 7,680 B

    const int tid = threadIdx.x;
    const int w0 = blockIdx.x * TW;
    const int h0 = blockIdx.y * TH;
    const int n  = blockIdx.z;

    // ---- stage x tile as packed f16 pairs, zero halo (matches zero pad) ----
    const float* xn = x + (size_t)n * (C_IN * HH * WW);
    for (int idx = tid; idx < XWORDS; idx += 512) {
        int c   = idx / (LROWS * LPAIRS);
        int rem = idx - c * (LROWS * LPAIRS);
        int r   = rem / LPAIRS;
        int jp  = rem - r * LPAIRS;
        int gh = h0 - PADK + r;
        int gw = w0 - PADK + 2 * jp;
        float v0 = 0.f, v1 = 0.f;
        if ((unsigned)gh < (unsigned)HH) {
            const float* row = xn + ((size_t)c * HH + gh) * WW;
            if ((unsigned)gw < (unsigned)WW) v0 = row[gw];
            if ((unsigned)(gw + 1) < (unsigned)WW) v1 = row[gw + 1];
        }
        _Float16 a = (_Float16)v0, b = (_Float16)v1;
        u32 u = ((u32)__builtin_bit_cast(uint16_t, b) << 16) |
                (u32)__builtin_bit_cast(uint16_t, a);
        (&xlds[0][0][0])[idx] = u;
    }
    // ---- stage weights as (h,h) f16 pairs, layout [c][og][dy][o2*5+dx] ----
    for (int t = tid; t < NW; t += 512) {
        int dx = t % KK;  int q = t / KK;
        int o2 = q & 1;   q >>= 1;
        int dy = q % KK;  q /= KK;
        int og = q & 3;   int c = q >> 2;
        int o = og * 2 + o2;
        float f = wf[((o * C_IN + c) * KK + dy) * KK + dx];
        _Float16 h = (_Float16)f;
        uint16_t hb = __builtin_bit_cast(uint16_t, h);
        wlds[((c * 4 + og) * KK + dy) * WCHUNK + o2 * KK + dx] =
            ((u32)hb << 16) | (u32)hb;
    }
    __syncthreads();

    // wave -> (o-pair og, row-quad rq); lane -> pixel-pair column
    const int l   = tid & 63;
    const int wid = tid >> 6;
    const int og  = wid & 3;
    const int rq  = wid >> 2;
    const int rbase = rq * 4;

    u32 acc[2][4];
    #pragma unroll
    for (int a = 0; a < 2; ++a)
        #pragma unroll
        for (int j = 0; j < 4; ++j) acc[a][j] = 0xFC00FC00u;  // (-inf,-inf)

    for (int c = 0; c < C_IN; ++c) {
        // 8 input rows serve the 4 output rows x 5 dy; shifted pairs once.
        u32 U0[8], S0[8], U1[8], S1[8], U2[8];
        #pragma unroll
        for (int r = 0; r < 8; ++r) {
            const u32* lrow = &xlds[c][rbase + r][l];
            u32 a = lrow[0], b = lrow[1], d = lrow[2];
            U0[r] = a; U1[r] = b; U2[r] = d;
            S0[r] = (a >> 16) | (b << 16);   // v_alignbit
            S1[r] = (b >> 16) | (d << 16);
        }
        const u32* wcbase = &wlds[(c * 4 + og) * KK * WCHUNK];
        #pragma unroll
        for (int dy = 0; dy < KK; ++dy) {
            // 10 uniform-address weight dwords -> VGPRs (b128+b128+b64)
            const u32* wch = wcbase + dy * WCHUNK;
            u32x4 wa = *(const u32x4*)(wch);
            u32x4 wb = *(const u32x4*)(wch + 4);
            u32x2 wc2 = *(const u32x2*)(wch + 8);
            u32 w[10] = {wa[0], wa[1], wa[2], wa[3],
                         wb[0], wb[1], wb[2], wb[3], wc2[0], wc2[1]};
            #pragma unroll
            for (int o2 = 0; o2 < 2; ++o2) {
                #pragma unroll
                for (int j = 0; j < 4; ++j) {
                    const int r = j + dy;           // static index
                    u32 t0 = pk_add(w[o2 * 5 + 0], U0[r]);
                    u32 t1 = pk_add(w[o2 * 5 + 1], S0[r]);
                    u32 t2 = pk_add(w[o2 * 5 + 2], U1[r]);
                    u32 t3 = pk_add(w[o2 * 5 + 3], S1[r]);
                    u32 t4 = pk_add(w[o2 * 5 + 4], U2[r]);
                    acc[o2][j] = pk_max(acc[o2][j],
                        pk_max(pk_max(pk_max(t0, t1), pk_max(t2, t3)), t4));
                }
            }
        }
    }

    // ---- store: 2 consecutive pixels -> one float2, coalesced ----
    float* onp = out + (size_t)n * (O_OUT * HH * WW);
    const int hB = h0 + rbase;
    const int wcol = w0 + 2 * l;
    #pragma unroll
    for (int o2 = 0; o2 < 2; ++o2) {
        const int o = og * 2 + o2;
        #pragma unroll
        for (int j = 0; j < 4; ++j) {
            half2v a = __builtin_bit_cast(half2v, acc[o2][j]);
            float2 rr;
            rr.x = (float)a.x;
            rr.y = (float)a.y;
            *(float2*)(&onp[((size_t)o * HH + hB + j) * WW + wcol]) = rr;
        }
    }
}

extern "C" void kernel_launch(void* const* d_in, const int* in_sizes, int n_in,
                              void* d_out, int out_size, void* d_ws, size_t ws_size,
                              hipStream_t stream) {
    const float* x   = (const float*)d_in[0];
    const float* wgt = (const float*)d_in[1];
    float* out = (float*)d_out;

    dim3 grid(WW / TW, HH / TH, 4);   // (4, 64, 4) = 1024 blocks x 512 thr
    dim3 block(512);
    dil_kernel<<<grid, block, 0, stream>>>(x, wgt, out);
}

// Round 9
// 69.132 us; speedup vs baseline: 1.7079x; 1.0457x over previous
//
#include <hip/hip_runtime.h>
#include <math.h>
#include <stdint.h>

#define KK 5
#define PADK 2
#define C_IN 8
#define O_OUT 8
#define HH 512
#define WW 512
#define TH 8
#define TW 128
#define LROWS 12                  // TH + 4
#define LCOLS 136                 // TW + 4 halo, padded to even (f32 cols)
#define WSTR 16                   // weight row stride (dwords), 16B-aligned
#define NW (O_OUT * C_IN * KK * KK)   // 1600
#define XPAIRS (C_IN * LROWS * (LCOLS / 2))   // float2 slots = 6528

// Full-rate VOP3 3-input max (guaranteed encoding).
static __device__ __forceinline__ float max3f(float a, float b, float c) {
    float d;
    asm("v_max3_f32 %0, %1, %2, %3" : "=v"(d) : "v"(a), "v"(b), "v"(c));
    return d;
}

__global__ __launch_bounds__(512, 2)
void dil_kernel(const float* __restrict__ x,
                const float* __restrict__ wf,
                float* __restrict__ out) {
    // All main-loop operands from LDS (in-order DS pipe, counted lgkm waits).
    __shared__ __align__(16) float xlds[C_IN][LROWS][LCOLS];        // 52,224 B
    __shared__ __align__(16) float wlds[C_IN * 4 * KK * WSTR];      // 10,240 B

    const int tid = threadIdx.x;
    const int w0 = blockIdx.x * TW;
    const int h0 = blockIdx.y * TH;
    const int n  = blockIdx.z;

    // ---- stage x tile (f32, zero halo == reference zero padding) ----
    const float* xn = x + (size_t)n * (C_IN * HH * WW);
    for (int idx = tid; idx < XPAIRS; idx += 512) {
        int c   = idx / (LROWS * (LCOLS / 2));
        int rem = idx - c * (LROWS * (LCOLS / 2));
        int r   = rem / (LCOLS / 2);
        int jp  = rem - r * (LCOLS / 2);
        int gh = h0 - PADK + r;
        int gw = w0 - PADK + 2 * jp;
        float v0 = 0.f, v1 = 0.f;
        if ((unsigned)gh < (unsigned)HH) {
            const float* row = xn + ((size_t)c * HH + gh) * WW;
            if ((unsigned)gw < (unsigned)WW) v0 = row[gw];
            if ((unsigned)(gw + 1) < (unsigned)WW) v1 = row[gw + 1];
        }
        float2* dst = (float2*)&xlds[c][r][2 * jp];
        *dst = make_float2(v0, v1);
    }
    // ---- stage weights: layout [c][og][dy][o2*5+dx] (10 used of WSTR) ----
    for (int t = tid; t < NW; t += 512) {
        int dx = t % KK;  int q = t / KK;
        int o2 = q & 1;   q >>= 1;
        int dy = q % KK;  q /= KK;
        int og = q & 3;   int c = q >> 2;
        int o = og * 2 + o2;
        wlds[((c * 4 + og) * KK + dy) * WSTR + o2 * KK + dx] =
            wf[((o * C_IN + c) * KK + dy) * KK + dx];
    }
    __syncthreads();

    // wave -> (o-pair og, row-quad rq); lane -> 2-pixel column strip
    const int l   = tid & 63;
    const int wid = tid >> 6;
    const int og  = wid & 3;
    const int rq  = wid >> 2;
    const int rbase = rq * 4;

    float acc[2][4][2];
    #pragma unroll
    for (int a = 0; a < 2; ++a)
        #pragma unroll
        for (int j = 0; j < 4; ++j) {
            acc[a][j][0] = -INFINITY;
            acc[a][j][1] = -INFINITY;
        }

    for (int c = 0; c < C_IN; ++c) {
        // 8 input rows x 6-wide f32 window (2 px + 4 halo) -> 48 regs
        float U[8][6];
        #pragma unroll
        for (int r = 0; r < 8; ++r) {
            const float* lr = &xlds[c][rbase + r][2 * l];
            float2 a = *(const float2*)(lr);
            float2 b = *(const float2*)(lr + 2);
            float2 d = *(const float2*)(lr + 4);
            U[r][0] = a.x; U[r][1] = a.y;
            U[r][2] = b.x; U[r][3] = b.y;
            U[r][4] = d.x; U[r][5] = d.y;
        }
        const float* wb = &wlds[(c * 4 + og) * KK * WSTR];
        #pragma unroll
        for (int dy = 0; dy < KK; ++dy) {
            // 10 wave-uniform weight dwords (b128 + b128 + b64, broadcast)
            const float* wch = wb + dy * WSTR;
            float4 wa = *(const float4*)(wch);
            float4 wv = *(const float4*)(wch + 4);
            float2 wc2 = *(const float2*)(wch + 8);
            float w[10] = {wa.x, wa.y, wa.z, wa.w,
                           wv.x, wv.y, wv.z, wv.w, wc2.x, wc2.y};
            #pragma unroll
            for (int o2 = 0; o2 < 2; ++o2) {
                #pragma unroll
                for (int j = 0; j < 4; ++j) {
                    const float* u = U[j + dy];      // static index
                    const float* wo = &w[o2 * 5];
                    // pixel 0: window u[0..4]
                    {
                        float t0 = u[0] + wo[0], t1 = u[1] + wo[1],
                              t2 = u[2] + wo[2], t3 = u[3] + wo[3],
                              t4 = u[4] + wo[4];
                        acc[o2][j][0] = max3f(acc[o2][j][0],
                                              max3f(t0, t1, t2),
                                              fmaxf(t3, t4));
                    }
                    // pixel 1: window u[1..5]
                    {
                        float t0 = u[1] + wo[0], t1 = u[2] + wo[1],
                              t2 = u[3] + wo[2], t3 = u[4] + wo[3],
                              t4 = u[5] + wo[4];
                        acc[o2][j][1] = max3f(acc[o2][j][1],
                                              max3f(t0, t1, t2),
                                              fmaxf(t3, t4));
                    }
                }
            }
        }
    }

    // ---- store: 2 consecutive pixels -> one float2, coalesced ----
    float* onp = out + (size_t)n * (O_OUT * HH * WW);
    const int hB = h0 + rbase;
    const int wcol = w0 + 2 * l;
    #pragma unroll
    for (int o2 = 0; o2 < 2; ++o2) {
        const int o = og * 2 + o2;
        #pragma unroll
        for (int j = 0; j < 4; ++j) {
            float2 rr = make_float2(acc[o2][j][0], acc[o2][j][1]);
            *(float2*)(&onp[((size_t)o * HH + hB + j) * WW + wcol]) = rr;
        }
    }
}

extern "C" void kernel_launch(void* const* d_in, const int* in_sizes, int n_in,
                              void* d_out, int out_size, void* d_ws, size_t ws_size,
                              hipStream_t stream) {
    const float* x   = (const float*)d_in[0];
    const float* wgt = (const float*)d_in[1];
    float* out = (float*)d_out;

    dim3 grid(WW / TW, HH / TH, 4);   // (4, 64, 4) = 1024 blocks x 512 thr
    dim3 block(512);
    dil_kernel<<<grid, block, 0, stream>>>(x, wgt, out);
}

// Round 10
// 66.593 us; speedup vs baseline: 1.7731x; 1.0381x over previous
//
#include <hip/hip_runtime.h>
#include <math.h>
#include <stdint.h>

#define KK 5
#define PADK 2
#define C_IN 8
#define O_OUT 8
#define HH 512
#define WW 512
#define TH 8
#define TW 128
#define CH 4                      // channels per staged half
#define LROWS 12                  // TH + 4
#define LCOLS 136                 // TW + 4 halo, padded (f32 cols)
#define WSTR 12                   // weight row stride (dwords) = 48 B, 16B-aligned
#define NW (O_OUT * C_IN * KK * KK)   // 1600
#define XHALF (CH * LROWS * (LCOLS / 2))   // float2 slots per half = 3264

// Full-rate VOP3 3-input max.
static __device__ __forceinline__ float max3f(float a, float b, float c) {
    float d;
    asm("v_max3_f32 %0, %1, %2, %3" : "=v"(d) : "v"(a), "v"(b), "v"(c));
    return d;
}

__global__ __launch_bounds__(512, 8)
void dil_kernel(const float* __restrict__ x,
                const float* __restrict__ wf,
                float* __restrict__ out) {
    // Small LDS footprint -> 4 blocks/CU, 32 waves/CU (100% cap).
    __shared__ __align__(16) float xlds[CH][LROWS][LCOLS];          // 26,112 B
    __shared__ __align__(16) float wlds[C_IN * 4 * KK * WSTR];      //  7,680 B

    const int tid = threadIdx.x;
    const int w0 = blockIdx.x * TW;
    const int h0 = blockIdx.y * TH;
    const int n  = blockIdx.z;
    const float* xn = x + (size_t)n * (C_IN * HH * WW);

    // wave -> (o-pair og, row-quad rq); lane -> 2-pixel column strip
    const int l   = tid & 63;
    const int wid = tid >> 6;
    const int og  = wid & 3;
    const int rq  = wid >> 2;          // 0..1
    const int rbase = rq * 4;

    float acc[2][4][2];
    #pragma unroll
    for (int a = 0; a < 2; ++a)
        #pragma unroll
        for (int j = 0; j < 4; ++j) {
            acc[a][j][0] = -INFINITY;
            acc[a][j][1] = -INFINITY;
        }

    for (int h = 0; h < 2; ++h) {
        if (h) __syncthreads();        // all waves done reading xlds half 0

        // ---- stage x half (4 channels), zero halo == reference zero pad ----
        for (int idx = tid; idx < XHALF; idx += 512) {
            int cc  = idx / (LROWS * (LCOLS / 2));
            int rem = idx - cc * (LROWS * (LCOLS / 2));
            int r   = rem / (LCOLS / 2);
            int jp  = rem - r * (LCOLS / 2);
            int gh = h0 - PADK + r;
            int gw = w0 - PADK + 2 * jp;
            float v0 = 0.f, v1 = 0.f;
            if ((unsigned)gh < (unsigned)HH) {
                const float* row = xn + ((size_t)(h * CH + cc) * HH + gh) * WW;
                if ((unsigned)gw < (unsigned)WW) v0 = row[gw];
                if ((unsigned)(gw + 1) < (unsigned)WW) v1 = row[gw + 1];
            }
            *(float2*)&xlds[cc][r][2 * jp] = make_float2(v0, v1);
        }
        // ---- stage weights once (h==0): layout [c][og][dy][o2*5+dx] ----
        if (h == 0) {
            for (int t = tid; t < NW; t += 512) {
                int dx = t % KK;  int q = t / KK;
                int o2 = q & 1;   q >>= 1;
                int dy = q % KK;  q /= KK;
                int g  = q & 3;   int c = q >> 2;
                int o = g * 2 + o2;
                wlds[((c * 4 + g) * KK + dy) * WSTR + o2 * KK + dx] =
                    wf[((o * C_IN + c) * KK + dy) * KK + dx];
            }
        }
        __syncthreads();

        for (int cc = 0; cc < CH; ++cc) {
            const float* wb = &wlds[((h * CH + cc) * 4 + og) * KK * WSTR];
            #pragma unroll
            for (int dy = 0; dy < KK; ++dy) {
                // 10 wave-uniform weight dwords (broadcast, conflict-free)
                const float* wch = wb + dy * WSTR;
                float4 wa = *(const float4*)(wch);
                float4 wv = *(const float4*)(wch + 4);
                float2 wc2 = *(const float2*)(wch + 8);
                const float w[10] = {wa.x, wa.y, wa.z, wa.w,
                                     wv.x, wv.y, wv.z, wv.w, wc2.x, wc2.y};
                #pragma unroll
                for (int j = 0; j < 4; ++j) {
                    // one x row: 6-wide window, 3x ds_read_b64 (2 lanes/bank)
                    const float* lr = &xlds[cc][rbase + dy + j][2 * l];
                    float2 a = *(const float2*)(lr);
                    float2 b = *(const float2*)(lr + 2);
                    float2 d = *(const float2*)(lr + 4);
                    const float u0 = a.x, u1 = a.y, u2 = b.x,
                                u3 = b.y, u4 = d.x, u5 = d.y;
                    #pragma unroll
                    for (int o2 = 0; o2 < 2; ++o2) {
                        const float* wo = &w[o2 * 5];
                        // pixel 0: window u0..u4
                        float t0 = u0 + wo[0], t1 = u1 + wo[1],
                              t2 = u2 + wo[2], t3 = u3 + wo[3],
                              t4 = u4 + wo[4];
                        acc[o2][j][0] = max3f(acc[o2][j][0],
                                              max3f(t0, t1, t2),
                                              fmaxf(t3, t4));
                        // pixel 1: window u1..u5
                        float s0 = u1 + wo[0], s1 = u2 + wo[1],
                              s2 = u3 + wo[2], s3 = u4 + wo[3],
                              s4 = u5 + wo[4];
                        acc[o2][j][1] = max3f(acc[o2][j][1],
                                              max3f(s0, s1, s2),
                                              fmaxf(s3, s4));
                    }
                }
            }
        }
    }

    // ---- store: 2 consecutive pixels -> one float2, coalesced ----
    float* onp = out + (size_t)n * (O_OUT * HH * WW);
    const int hB = h0 + rbase;
    const int wcol = w0 + 2 * l;
    #pragma unroll
    for (int o2 = 0; o2 < 2; ++o2) {
        const int o = og * 2 + o2;
        #pragma unroll
        for (int j = 0; j < 4; ++j) {
            float2 rr = make_float2(acc[o2][j][0], acc[o2][j][1]);
            *(float2*)(&onp[((size_t)o * HH + hB + j) * WW + wcol]) = rr;
        }
    }
}

extern "C" void kernel_launch(void* const* d_in, const int* in_sizes, int n_in,
                              void* d_out, int out_size, void* d_ws, size_t ws_size,
                              hipStream_t stream) {
    const float* x   = (const float*)d_in[0];
    const float* wgt = (const float*)d_in[1];
    float* out = (float*)d_out;

    dim3 grid(WW / TW, HH / TH, 4);   // (4, 64, 4) = 1024 blocks x 512 thr
    dim3 block(512);
    dil_kernel<<<grid, block, 0, stream>>>(x, wgt, out);
}